// Round 11
// baseline (136.783 us; speedup 1.0000x reference)
//
#include <hip/hip_runtime.h>
#include <hip/hip_fp16.h>

typedef unsigned long long u64;
typedef unsigned short ushort_t;
typedef __attribute__((ext_vector_type(8))) short short8v;   // 8 bf16 (4 VGPR)
typedef __attribute__((ext_vector_type(16))) float f32x16;   // MFMA accumulator

#define DI __device__ __forceinline__

DI unsigned cvt_pk_bf16(float lo, float hi) {   // u32 = {bf16(hi)<<16 | bf16(lo)}, RNE
    unsigned r;
    asm volatile("v_cvt_pk_bf16_f32 %0, %1, %2" : "=v"(r) : "v"(lo), "v"(hi));
    return r;
}

// Dims: b=8, N=1024, L=4, C=128, O=64, F=64, C+O=192
// Softmax reference constant: K[m] = leaky(f2[m]) + 12 (any per-column constant
// cancels in exp(e-K)/sum exp(e'-K); 12 keeps all exponents in-range).
// ---------------------------------------------------------------------------
// k_h: fused. Per block: gs[b] = gstate[b]@Wg (LDS), wa1/wa2 = W@a (LDS), then
// hT[l][b][f][m] (bf16) = (Vg @ W[l])^T and f1/f2[l][b][n] = Vg.wa{1,2}[l].
// grid 256 = (b=8) x (nt=32 tiles of 32 rows); block 256
__global__ __launch_bounds__(256)
void k_h(const float* V, const int* gsize, const float* gstate, const float* Wg,
         const float* W, const float* a1, const float* a2,
         ushort_t* hT, float* f1, float* f2)
{
    int blk = blockIdx.x;
    int b = blk >> 5, nt = blk & 31, n0 = nt * 32;
    int t = threadIdx.x;
    __shared__ float gss[64];
    __shared__ float was[2][4][192];   // 6 KB
    __shared__ float vg[32][194];
    // phase 0: wave0 computes gs; waves 1-3 compute wa1/wa2 (1536 dots / 192 thr = 8 each)
    if (t < 64) {
        float acc = 0.f;
        for (int c = 0; c < 128; ++c) acc += gstate[b*128 + c] * Wg[c*64 + t];
        gss[t] = acc;
    } else {
        int tt = t - 64;
        #pragma unroll
        for (int k = 0; k < 8; ++k) {
            int e = tt + k*192;                    // 0..1535
            int which = (e >= 768) ? 1 : 0;
            int idx = which ? e - 768 : e;
            int l = idx / 192, c = idx - l*192;
            const float* ap = (which ? a2 : a1) + l*64;
            const float* wp = W + (l*192 + c) * 64;
            float s = 0.f;
            for (int f = 0; f < 64; ++f) s += wp[f] * ap[f];
            was[which][l][c] = s;
        }
    }
    __syncthreads();
    {
        int r = t >> 3, c0 = (t & 7) * 16;
        const float* vp = V + ((size_t)(b*1024 + n0 + r) * 128 + c0);
        float4 v0 = *(const float4*)(vp + 0);
        float4 v1 = *(const float4*)(vp + 4);
        float4 v2 = *(const float4*)(vp + 8);
        float4 v3 = *(const float4*)(vp + 12);
        *(float4*)&vg[r][c0 + 0]  = v0;
        *(float4*)&vg[r][c0 + 4]  = v1;
        *(float4*)&vg[r][c0 + 8]  = v2;
        *(float4*)&vg[r][c0 + 12] = v3;
    }
    {
        int r = t >> 3, o0 = (t & 7) * 8;
        bool on = (n0 + r) < gsize[b];
        for (int j = 0; j < 8; ++j) vg[r][128 + o0 + j] = on ? gss[o0 + j] : 0.f;
    }
    __syncthreads();
    int ty = t >> 5, tx = t & 31;
    int r0 = ty * 4;
    int j0 = tx * 8;
    int lw = j0 >> 6, f0 = j0 & 63;
    float acc[4][8];
    for (int i = 0; i < 4; ++i) for (int j = 0; j < 8; ++j) acc[i][j] = 0.f;
    const float* wp = W + (size_t)(lw*192) * 64 + f0;
    for (int c = 0; c < 192; ++c) {
        float4 wl = *(const float4*)(wp + c*64);
        float4 wh = *(const float4*)(wp + c*64 + 4);
        float wf[8] = {wl.x, wl.y, wl.z, wl.w, wh.x, wh.y, wh.z, wh.w};
        float a0 = vg[r0+0][c], a1v = vg[r0+1][c], a2v = vg[r0+2][c], a3v = vg[r0+3][c];
        for (int j = 0; j < 8; ++j) {
            acc[0][j] += a0  * wf[j];
            acc[1][j] += a1v * wf[j];
            acc[2][j] += a2v * wf[j];
            acc[3][j] += a3v * wf[j];
        }
    }
    int lb = lw*8 + b;
    #pragma unroll
    for (int j = 0; j < 8; ++j) {
        uint2 st;
        st.x = cvt_pk_bf16(acc[0][j], acc[1][j]);
        st.y = cvt_pk_bf16(acc[2][j], acc[3][j]);
        *(uint2*)(hT + ((size_t)(lb*64 + f0 + j)) * 1024 + n0 + r0) = st;
    }
    {
        int r = t & 31, l = (t >> 5) & 3, which = t >> 7;
        const float* wl = &was[which][l][0];
        float s = 0.f;
        for (int c = 0; c < 192; ++c) s += vg[r][c] * wl[c];
        float* dst = which ? f2 : f1;
        dst[(l*8 + b) * 1024 + n0 + r] = s;
    }
}

// ---------------------------------------------------------------------------
// k_maskcolsum v6: register double-buffered batches for deep memory pipelining.
// One pass over A -> u16 mask words (bit j, col m=lane*16+j; bit-identical to the
// u64 consumer layout) AND per-column partial sum_n exp(leaky(f1+f2) - K[m]).
// Wave = 16 rows in 4 batches of 4; two 16xfloat4 buffers alternate so >=16
// loads (256 B/lane) stay in flight under each PROC (Little's-law fix: the
// 75us plateau was ~64 B/lane in flight).
// grid 512 = b(8) x l(4) x nc(16 chunks of 64 rows); block 256 (4 waves x 16 rows)
__global__ __launch_bounds__(256, 2)
void k_maskcolsum(const float* A, const float* f1, const float* f2,
                  u64* maskp, float* psum)
{
    int blk = blockIdx.x;
    int nc = blk & 15, l = (blk >> 4) & 3, b = blk >> 6;
    int t = threadIdx.x;
    int wv = t >> 6, lane = t & 63;
    int lb = l*8 + b;
    int n0 = nc*64 + wv*16;
    ushort_t* mp16 = (ushort_t*)maskp;

    // lane's 16 columns: K[j] = leaky(f2[m]) + 12
    float K[16], F2r[16];
    {
        const float* f2p = f2 + lb*1024 + lane*16;
        #pragma unroll
        for (int q = 0; q < 4; ++q) {
            float4 v = *(const float4*)(f2p + q*4);
            float x4[4] = {v.x, v.y, v.z, v.w};
            #pragma unroll
            for (int i = 0; i < 4; ++i) {
                F2r[q*4 + i] = x4[i];
                K[q*4 + i]   = fmaxf(x4[i], 0.2f*x4[i]) + 12.f;
            }
        }
    }
    // wave's 16 f1 values (rows n0..n0+15, 64B-aligned)
    float f1r[16];
    {
        const float* f1p = f1 + lb*1024 + n0;
        #pragma unroll
        for (int q = 0; q < 4; ++q) {
            float4 v = *(const float4*)(f1p + q*4);
            f1r[q*4+0] = v.x; f1r[q*4+1] = v.y; f1r[q*4+2] = v.z; f1r[q*4+3] = v.w;
        }
    }
    float s[16];
    #pragma unroll
    for (int j = 0; j < 16; ++j) s[j] = 0.f;

    const float* Abase = A + (((size_t)(b*1024 + n0) * 4 + l) * 1024) + lane*16;

    auto LOADB = [&](float4* dst, int batch) {
        #pragma unroll
        for (int r = 0; r < 4; ++r) {
            const float* ap = Abase + (size_t)(batch*4 + r) * 4096;
            dst[r*4+0] = *(const float4*)(ap + 0);
            dst[r*4+1] = *(const float4*)(ap + 4);
            dst[r*4+2] = *(const float4*)(ap + 8);
            dst[r*4+3] = *(const float4*)(ap + 12);
        }
    };
    auto PROC = [&](float4* src, int batch) {
        #pragma unroll
        for (int r = 0; r < 4; ++r) {
            int n = n0 + batch*4 + r;
            float f1n = f1r[batch*4 + r];
            unsigned bits = 0;
            #pragma unroll
            for (int q = 0; q < 4; ++q) {
                float4 v = src[r*4 + q];
                float x4[4] = {v.x, v.y, v.z, v.w};
                #pragma unroll
                for (int i = 0; i < 4; ++i) {
                    int j = q*4 + i;
                    bool pos = x4[i] > 0.f;
                    bits |= pos ? (1u << j) : 0u;
                    float x = f1n + F2r[j];
                    x = fmaxf(x, 0.2f * x);          // leaky_relu(0.2)
                    float p = __expf(x - K[j]);
                    s[j] += pos ? p : 0.f;
                }
            }
            mp16[(((size_t)(b*1024 + n) * 4 + l) << 6) + lane] = (ushort_t)bits;
        }
    };

    float4 Abuf[16], Bbuf[16];
    LOADB(Abuf, 0);
    LOADB(Bbuf, 1);
    PROC(Abuf, 0);
    LOADB(Abuf, 2);
    PROC(Bbuf, 1);
    LOADB(Bbuf, 3);
    PROC(Abuf, 2);
    PROC(Bbuf, 3);

    // block-reduce the 4 waves' partial sums -> psum[nc][lb*1024 + m]
    __shared__ float ss[4][64][17];   // pad 17: conflict-free scalar access
    #pragma unroll
    for (int j = 0; j < 16; ++j) ss[wv][lane][j] = s[j];
    __syncthreads();
    #pragma unroll
    for (int q = 0; q < 4; ++q) {
        int m = q*256 + t;             // column index 0..1023
        int l2 = m >> 4, j = m & 15;
        float v = (ss[0][l2][j] + ss[1][l2][j]) + (ss[2][l2][j] + ss[3][l2][j]);
        psum[(size_t)nc*32768 + lb*1024 + m] = v;
    }
}

// ---------------------------------------------------------------------------
// k_csum: s = sum of 16 partials; empty col <=> s==0 (every present addend
// >= exp(-42), far above denormal range); ecol = exp(-K)/s; base = empty ? 1/1024 : 0
__global__ __launch_bounds__(256)
void k_csum(const float* psum, const float* f2, float* ecol, float* base)
{
    int i = blockIdx.x * 256 + threadIdx.x;   // 32768
    float s = 0.f;
    #pragma unroll
    for (int k = 0; k < 16; ++k) s += psum[(size_t)k*32768 + i];
    float x = f2[i];
    float K = fmaxf(x, 0.2f*x) + 12.f;
    bool emp = (s == 0.f);
    ecol[i] = emp ? 0.f : __expf(-K) / s;
    base[i] = emp ? (1.f/1024.f) : 0.f;
}

// ---------------------------------------------------------------------------
// k_pass2: MFMA. outl2[sl=ks*4+l][b][n][f] (f16) = sum_{m in K-half} att[n,m]*h[m,f]
// att generated in registers in A-frag layout: row=lane&31, k=8*(lane>>5)+i.
// grid 512 = ks(2) x l(4) x b(8) x nt(8 tiles of 128 n-rows); block 256 (4 waves: 32n x 64f each)
__global__ __launch_bounds__(256)
void k_pass2(const ushort_t* hT, const u64* maskp, const float* f1,
             const float* f2, const float* ecol, const float* base, __half* outl2)
{
    int blk = blockIdx.x;
    int nt = blk & 7, b = (blk >> 3) & 7, l = (blk >> 6) & 3, ks = blk >> 8;
    int lb = l*8 + b;
    int n0 = nt*128;
    int m0 = ks*512;
    int t = threadIdx.x;
    int w = t >> 6, lane = t & 63;
    int rl = lane & 31, kg = lane >> 5;

    __shared__ float f2t[512], ect[512], bat[512];
    __shared__ ushort_t hl[64][72];   // 64 f x 64 m bf16 chunk, pad 72

    for (int k = 0; k < 2; ++k) {
        int j = t + k*256;
        f2t[j] = f2[lb*1024 + m0 + j];
        ect[j] = ecol[lb*1024 + m0 + j];
        bat[j] = base[lb*1024 + m0 + j];
    }
    int nrow = n0 + w*32 + rl;
    float f1v = f1[lb*1024 + nrow];
    const u64* mrow = maskp + ((size_t)(b*1024 + nrow)*4 + l)*16 + ks*8;

    f32x16 acc0 = {0,0,0,0,0,0,0,0,0,0,0,0,0,0,0,0};
    f32x16 acc1 = {0,0,0,0,0,0,0,0,0,0,0,0,0,0,0,0};

    int hf = t >> 2, hseg = t & 3;
    const ushort_t* hsrc = hT + ((size_t)(lb*64 + hf)) * 1024 + m0 + hseg*16;

    for (int kc = 0; kc < 8; ++kc) {
        __syncthreads();
        {   // stage 64f x 64m bf16 chunk
            const uint4* s = (const uint4*)(hsrc + kc*64);
            uint4 q0 = s[0], q1 = s[1];
            *(uint4*)&hl[hf][hseg*16]     = q0;
            *(uint4*)&hl[hf][hseg*16 + 8] = q1;
        }
        u64 wm = mrow[kc];
        __syncthreads();
        #pragma unroll
        for (int kk = 0; kk < 4; ++kk) {
            int jb = kc*64 + kk*16 + kg*8;
            float4 fa = *(float4*)&f2t[jb];
            float4 fb = *(float4*)&f2t[jb+4];
            float4 ea = *(float4*)&ect[jb];
            float4 eb = *(float4*)&ect[jb+4];
            float4 ba = *(float4*)&bat[jb];
            float4 bb = *(float4*)&bat[jb+4];
            unsigned mb = (unsigned)(wm >> (kk*16 + kg*8)) & 0xffu;
            float xs[8] = {fa.x,fa.y,fa.z,fa.w,fb.x,fb.y,fb.z,fb.w};
            float es[8] = {ea.x,ea.y,ea.z,ea.w,eb.x,eb.y,eb.z,eb.w};
            float bs[8] = {ba.x,ba.y,ba.z,ba.w,bb.x,bb.y,bb.z,bb.w};
            float av[8];
            #pragma unroll
            for (int i = 0; i < 8; ++i) {
                float x = f1v + xs[i];
                x = fmaxf(x, 0.2f * x);          // leaky_relu(0.2)
                float p = __expf(x) * es[i];
                av[i] = (mb & (1u << i)) ? p : bs[i];
            }
            union { unsigned u[4]; short8v s; } af;
            af.u[0] = cvt_pk_bf16(av[0], av[1]);
            af.u[1] = cvt_pk_bf16(av[2], av[3]);
            af.u[2] = cvt_pk_bf16(av[4], av[5]);
            af.u[3] = cvt_pk_bf16(av[6], av[7]);
            short8v b0 = *(short8v*)&hl[rl][kk*16 + kg*8];
            short8v b1 = *(short8v*)&hl[32 + rl][kk*16 + kg*8];
            acc0 = __builtin_amdgcn_mfma_f32_32x32x16_bf16(af.s, b0, acc0, 0, 0, 0);
            acc1 = __builtin_amdgcn_mfma_f32_32x32x16_bf16(af.s, b1, acc1, 0, 0, 0);
        }
    }
    int sl = ks*4 + l;
    __half* op = outl2 + ((size_t)(sl*8 + b) * 1024) * 64;
    #pragma unroll
    for (int r = 0; r < 16; ++r) {
        int row = n0 + w*32 + (r & 3) + 8*(r >> 2) + 4*kg;   // C/D layout (m74/m101)
        op[(size_t)row*64 + rl]      = __float2half(acc0[r]);
        op[(size_t)row*64 + 32 + rl] = __float2half(acc1[r]);
    }
}

// ---------------------------------------------------------------------------
// k_reduce: outpre = sum_{8 slices} outl2 + bias; BN partial sums (LDS + global atomics)
// grid 256 x 256 thr x 8 elems = 524288
__global__ __launch_bounds__(256)
void k_reduce(const __half* outl2, const float* bias, float* outpre, float* bnsum, float* bnsumsq)
{
    int blk = blockIdx.x, t = threadIdx.x;
    __shared__ float red[2][64];
    if (t < 128) red[t >> 6][t & 63] = 0.f;
    __syncthreads();
    size_t idx = (size_t)blk * 2048 + t * 8;
    int fb = (t * 8) & 63;
    float o[8];
    for (int j = 0; j < 8; ++j) o[j] = bias[fb + j];
    #pragma unroll
    for (int sl = 0; sl < 8; ++sl) {
        uint4 u = *(const uint4*)(outl2 + (size_t)sl * 524288 + idx);
        const __half* hh = (const __half*)&u;
        #pragma unroll
        for (int j = 0; j < 8; ++j) o[j] += __half2float(hh[j]);
    }
    *(float4*)(outpre + idx)     = make_float4(o[0], o[1], o[2], o[3]);
    *(float4*)(outpre + idx + 4) = make_float4(o[4], o[5], o[6], o[7]);
    for (int j = 0; j < 8; ++j) {
        atomicAdd(&red[0][fb + j], o[j]);
        atomicAdd(&red[1][fb + j], o[j]*o[j]);
    }
    __syncthreads();
    if (t < 64) { atomicAdd(&bnsum[t], red[0][t]); atomicAdd(&bnsumsq[t], red[1][t]); }
}

// ---------------------------------------------------------------------------
// k_bnapply: main BN+relu (grid 128 covers 524288 elems). Block 0 additionally
// computes gs = gstate@Wg, its batch BN+relu -> out_gs.
__global__ __launch_bounds__(256)
void k_bnapply(const float* outpre, const float* bnsum, const float* bnsumsq,
               const float* gamma, const float* beta, float* out,
               const float* gstate, const float* Wg,
               const float* gamma_g, const float* beta_g, float* out_gs)
{
    int blk = blockIdx.x, t = threadIdx.x;
    __shared__ float gsa[512];
    __shared__ float gmu[64], grs[64];
    if (blk == 0) {
        for (int p = t; p < 512; p += 256) {
            int bb = p >> 6, o = p & 63;
            float acc = 0.f;
            for (int c = 0; c < 128; ++c) acc += gstate[bb*128 + c] * Wg[c*64 + o];
            gsa[p] = acc;
        }
        __syncthreads();
        if (t < 64) {
            float s = 0.f, sq = 0.f;
            for (int bb = 0; bb < 8; ++bb) { float v = gsa[bb*64 + t]; s += v; sq += v*v; }
            float mu = s * 0.125f;
            float var = sq * 0.125f - mu*mu;
            gmu[t] = mu; grs[t] = rsqrtf(var + 1e-5f);
        }
        __syncthreads();
        for (int p = t; p < 512; p += 256) {
            int o = p & 63;
            float v = (gsa[p] - gmu[o]) * grs[o] * gamma_g[o] + beta_g[o];
            out_gs[p] = fmaxf(v, 0.f);
        }
    }
    int f0 = (t * 4) & 63;
    float mu[4], rstd[4], ga[4], be[4];
    for (int j = 0; j < 4; ++j) {
        float sm = bnsum[f0 + j], sq = bnsumsq[f0 + j];
        float m = sm * (1.f / 8192.f);
        float var = sq * (1.f / 8192.f) - m*m;
        mu[j] = m; rstd[j] = rsqrtf(var + 1e-5f);
        ga[j] = gamma[f0 + j]; be[j] = beta[f0 + j];
    }
    for (int g = 0; g < 4; ++g) {
        size_t base = (size_t)blk * 4096 + g * 1024 + t * 4;
        float4 v = *(const float4*)(outpre + base);
        float x[4] = {v.x, v.y, v.z, v.w};
        float y[4];
        for (int j = 0; j < 4; ++j) {
            float z = (x[j] - mu[j]) * rstd[j] * ga[j] + be[j];
            y[j] = fmaxf(z, 0.f);
        }
        *(float4*)(out + base) = make_float4(y[0], y[1], y[2], y[3]);
    }
}

// ---------------------------------------------------------------------------
extern "C" void kernel_launch(void* const* d_in, const int* in_sizes, int n_in,
                              void* d_out, int out_size, void* d_ws, size_t ws_size,
                              hipStream_t stream)
{
    const float* V       = (const float*)d_in[0];
    const float* A       = (const float*)d_in[1];
    const float* gstate  = (const float*)d_in[2];
    const int*   gsize   = (const int*)d_in[3];
    // d_in[4] subgraph_size: unused by reference
    const float* Wg      = (const float*)d_in[5];
    const float* W       = (const float*)d_in[6];
    const float* a1      = (const float*)d_in[7];
    const float* a2      = (const float*)d_in[8];
    const float* bias    = (const float*)d_in[9];
    const float* gamma_n = (const float*)d_in[10];
    const float* beta_n  = (const float*)d_in[11];
    const float* gamma_g = (const float*)d_in[12];
    const float* beta_g  = (const float*)d_in[13];

    char* ws = (char*)d_ws;               // ~22 MB used (ws is ~512 MB)
    float*    f1      = (float*)(ws + 0);
    float*    f2      = (float*)(ws + 131072);
    float*    ecol    = (float*)(ws + 262144);
    float*    base    = (float*)(ws + 393216);
    float*    bnsum   = (float*)(ws + 524288);
    float*    bnsumsq = (float*)(ws + 524544);
    u64*      maskp   = (u64*)  (ws + 525312);      // 4 MB
    ushort_t* hT      = (ushort_t*)(ws + 4719616);  // 4 MB bf16
    float*    psum    = (float*)(ws + 8913920);     // 2 MB (16 partials x 32K)
    __half*   outl2   = (__half*)(ws + 11011072);   // 8 MB (8 slices f16)
    float*    outpre  = (float*)(ws + 19399680);    // 2 MB

    float* out_main = (float*)d_out;
    float* out_gs   = out_main + 524288;

    (void)hipMemsetAsync(bnsum, 0, 512, stream);   // bnsum + bnsumsq
    hipLaunchKernelGGL(k_h,          dim3(256),  dim3(256), 0, stream,
                       V, gsize, gstate, Wg, W, a1, a2, hT, f1, f2);
    hipLaunchKernelGGL(k_maskcolsum, dim3(512),  dim3(256), 0, stream,
                       A, f1, f2, maskp, psum);
    hipLaunchKernelGGL(k_csum,       dim3(128),  dim3(256), 0, stream,
                       psum, f2, ecol, base);
    hipLaunchKernelGGL(k_pass2,      dim3(512),  dim3(256), 0, stream,
                       hT, maskp, f1, f2, ecol, base, outl2);
    hipLaunchKernelGGL(k_reduce,     dim3(256),  dim3(256), 0, stream,
                       outl2, bias, outpre, bnsum, bnsumsq);
    hipLaunchKernelGGL(k_bnapply,    dim3(128),  dim3(256), 0, stream,
                       outpre, bnsum, bnsumsq, gamma_n, beta_n, out_main,
                       gstate, Wg, gamma_g, beta_g, out_gs);
}

// Round 12
// 123.833 us; speedup vs baseline: 1.1046x; 1.1046x over previous
//
#include <hip/hip_runtime.h>
#include <hip/hip_fp16.h>

typedef unsigned long long u64;
typedef unsigned short ushort_t;
typedef __attribute__((ext_vector_type(8))) short short8v;   // 8 bf16 (4 VGPR)
typedef __attribute__((ext_vector_type(16))) float f32x16;   // MFMA accumulator

#define DI __device__ __forceinline__

DI unsigned cvt_pk_bf16(float lo, float hi) {   // u32 = {bf16(hi)<<16 | bf16(lo)}, RNE
    unsigned r;
    asm volatile("v_cvt_pk_bf16_f32 %0, %1, %2" : "=v"(r) : "v"(lo), "v"(hi));
    return r;
}

// Dims: b=8, N=1024, L=4, C=128, O=64, F=64, C+O=192
// Softmax reference constant: K[m] = leaky(f2[m]) + 12 (any per-column constant
// cancels in exp(e-K)/sum exp(e'-K); 12 keeps all exponents in-range).
// ---------------------------------------------------------------------------
// k_h: fused. Per block: gs[b] = gstate[b]@Wg (LDS), wa1/wa2 = W@a (LDS), then
// hT[l][b][f][m] (bf16) = (Vg @ W[l])^T and f1/f2[l][b][n] = Vg.wa{1,2}[l].
// grid 256 = (b=8) x (nt=32 tiles of 32 rows); block 256
__global__ __launch_bounds__(256)
void k_h(const float* V, const int* gsize, const float* gstate, const float* Wg,
         const float* W, const float* a1, const float* a2,
         ushort_t* hT, float* f1, float* f2)
{
    int blk = blockIdx.x;
    int b = blk >> 5, nt = blk & 31, n0 = nt * 32;
    int t = threadIdx.x;
    __shared__ float gss[64];
    __shared__ float was[2][4][192];   // 6 KB
    __shared__ float vg[32][194];
    // phase 0: wave0 computes gs; waves 1-3 compute wa1/wa2 (1536 dots / 192 thr = 8 each)
    if (t < 64) {
        float acc = 0.f;
        for (int c = 0; c < 128; ++c) acc += gstate[b*128 + c] * Wg[c*64 + t];
        gss[t] = acc;
    } else {
        int tt = t - 64;
        #pragma unroll
        for (int k = 0; k < 8; ++k) {
            int e = tt + k*192;                    // 0..1535
            int which = (e >= 768) ? 1 : 0;
            int idx = which ? e - 768 : e;
            int l = idx / 192, c = idx - l*192;
            const float* ap = (which ? a2 : a1) + l*64;
            const float* wp = W + (l*192 + c) * 64;
            float s = 0.f;
            for (int f = 0; f < 64; ++f) s += wp[f] * ap[f];
            was[which][l][c] = s;
        }
    }
    __syncthreads();
    {
        int r = t >> 3, c0 = (t & 7) * 16;
        const float* vp = V + ((size_t)(b*1024 + n0 + r) * 128 + c0);
        float4 v0 = *(const float4*)(vp + 0);
        float4 v1 = *(const float4*)(vp + 4);
        float4 v2 = *(const float4*)(vp + 8);
        float4 v3 = *(const float4*)(vp + 12);
        *(float4*)&vg[r][c0 + 0]  = v0;
        *(float4*)&vg[r][c0 + 4]  = v1;
        *(float4*)&vg[r][c0 + 8]  = v2;
        *(float4*)&vg[r][c0 + 12] = v3;
    }
    {
        int r = t >> 3, o0 = (t & 7) * 8;
        bool on = (n0 + r) < gsize[b];
        for (int j = 0; j < 8; ++j) vg[r][128 + o0 + j] = on ? gss[o0 + j] : 0.f;
    }
    __syncthreads();
    int ty = t >> 5, tx = t & 31;
    int r0 = ty * 4;
    int j0 = tx * 8;
    int lw = j0 >> 6, f0 = j0 & 63;
    float acc[4][8];
    for (int i = 0; i < 4; ++i) for (int j = 0; j < 8; ++j) acc[i][j] = 0.f;
    const float* wp = W + (size_t)(lw*192) * 64 + f0;
    for (int c = 0; c < 192; ++c) {
        float4 wl = *(const float4*)(wp + c*64);
        float4 wh = *(const float4*)(wp + c*64 + 4);
        float wf[8] = {wl.x, wl.y, wl.z, wl.w, wh.x, wh.y, wh.z, wh.w};
        float a0 = vg[r0+0][c], a1v = vg[r0+1][c], a2v = vg[r0+2][c], a3v = vg[r0+3][c];
        for (int j = 0; j < 8; ++j) {
            acc[0][j] += a0  * wf[j];
            acc[1][j] += a1v * wf[j];
            acc[2][j] += a2v * wf[j];
            acc[3][j] += a3v * wf[j];
        }
    }
    int lb = lw*8 + b;
    #pragma unroll
    for (int j = 0; j < 8; ++j) {
        uint2 st;
        st.x = cvt_pk_bf16(acc[0][j], acc[1][j]);
        st.y = cvt_pk_bf16(acc[2][j], acc[3][j]);
        *(uint2*)(hT + ((size_t)(lb*64 + f0 + j)) * 1024 + n0 + r0) = st;
    }
    {
        int r = t & 31, l = (t >> 5) & 3, which = t >> 7;
        const float* wl = &was[which][l][0];
        float s = 0.f;
        for (int c = 0; c < 192; ++c) s += vg[r][c] * wl[c];
        float* dst = which ? f2 : f1;
        dst[(l*8 + b) * 1024 + n0 + r] = s;
    }
}

// ---------------------------------------------------------------------------
// k_mask v7: PURE STREAM COMPRESS (decisive A-read experiment). One thread =
// 16 consecutive floats (4x dwordx4) -> one u16 of sign bits. l is fused into
// the flat index so A is read fully dense (16 KB/row, no 4KB-comb gaps).
// Word i covers flat elements [16i,16i+16): identical bit layout to the u64
// mask consumers use. grid 8192 x 256 (2,097,152 words), VGPR ~24, no LDS.
__global__ __launch_bounds__(256)
void k_mask(const float* A, ushort_t* mask16)
{
    size_t i = (size_t)blockIdx.x * 256 + threadIdx.x;
    const float4* p = (const float4*)(A + i * 16);
    float4 a0 = p[0];
    float4 a1 = p[1];
    float4 a2 = p[2];
    float4 a3 = p[3];
    unsigned bits = 0;
    bits |= (a0.x > 0.f) ? 1u << 0  : 0u;
    bits |= (a0.y > 0.f) ? 1u << 1  : 0u;
    bits |= (a0.z > 0.f) ? 1u << 2  : 0u;
    bits |= (a0.w > 0.f) ? 1u << 3  : 0u;
    bits |= (a1.x > 0.f) ? 1u << 4  : 0u;
    bits |= (a1.y > 0.f) ? 1u << 5  : 0u;
    bits |= (a1.z > 0.f) ? 1u << 6  : 0u;
    bits |= (a1.w > 0.f) ? 1u << 7  : 0u;
    bits |= (a2.x > 0.f) ? 1u << 8  : 0u;
    bits |= (a2.y > 0.f) ? 1u << 9  : 0u;
    bits |= (a2.z > 0.f) ? 1u << 10 : 0u;
    bits |= (a2.w > 0.f) ? 1u << 11 : 0u;
    bits |= (a3.x > 0.f) ? 1u << 12 : 0u;
    bits |= (a3.y > 0.f) ? 1u << 13 : 0u;
    bits |= (a3.z > 0.f) ? 1u << 14 : 0u;
    bits |= (a3.w > 0.f) ? 1u << 15 : 0u;
    mask16[i] = (ushort_t)bits;
}

// ---------------------------------------------------------------------------
// k_colsum v7: mask(4MB) + f1/f2 -> per-column partial sum_n exp(leaky(f1+f2)-K[m]).
// grid 512 = b(8) x l(4) x nc(16 chunks of 64 rows); block 256 (4 waves x 16 rows).
// Lane owns 16 columns (m=lane*16+j); per row one u16 word gives its mask bits.
__global__ __launch_bounds__(256)
void k_colsum(const ushort_t* mask16, const float* f1, const float* f2, float* psum)
{
    int blk = blockIdx.x;
    int nc = blk & 15, l = (blk >> 4) & 3, b = blk >> 6;
    int t = threadIdx.x;
    int wv = t >> 6, lane = t & 63;
    int lb = l*8 + b;
    int n0 = nc*64 + wv*16;

    float K[16], F2r[16];
    {
        const float* f2p = f2 + lb*1024 + lane*16;
        #pragma unroll
        for (int q = 0; q < 4; ++q) {
            float4 v = *(const float4*)(f2p + q*4);
            float x4[4] = {v.x, v.y, v.z, v.w};
            #pragma unroll
            for (int i = 0; i < 4; ++i) {
                F2r[q*4 + i] = x4[i];
                K[q*4 + i]   = fmaxf(x4[i], 0.2f*x4[i]) + 12.f;
            }
        }
    }
    float f1r[16];
    {
        const float* f1p = f1 + lb*1024 + n0;
        #pragma unroll
        for (int q = 0; q < 4; ++q) {
            float4 v = *(const float4*)(f1p + q*4);
            f1r[q*4+0] = v.x; f1r[q*4+1] = v.y; f1r[q*4+2] = v.z; f1r[q*4+3] = v.w;
        }
    }
    // 16 mask words (one per row), issued upfront; row stride = 4*64 = 256 words
    const ushort_t* mp = mask16 + (((size_t)(b*1024 + n0) * 4 + l) << 6) + lane;
    unsigned wbits[16];
    #pragma unroll
    for (int r = 0; r < 16; ++r) wbits[r] = mp[(size_t)r * 256];

    float s[16];
    #pragma unroll
    for (int j = 0; j < 16; ++j) s[j] = 0.f;
    #pragma unroll
    for (int r = 0; r < 16; ++r) {
        unsigned bits = wbits[r];
        float f1n = f1r[r];
        #pragma unroll
        for (int j = 0; j < 16; ++j) {
            float x = f1n + F2r[j];
            x = fmaxf(x, 0.2f * x);          // leaky_relu(0.2)
            float p = __expf(x - K[j]);
            s[j] += ((bits >> j) & 1u) ? p : 0.f;
        }
    }
    // block-reduce the 4 waves' partial sums -> psum[nc][lb*1024 + m]
    __shared__ float ss[4][64][17];   // pad 17: conflict-free scalar access
    #pragma unroll
    for (int j = 0; j < 16; ++j) ss[wv][lane][j] = s[j];
    __syncthreads();
    #pragma unroll
    for (int q = 0; q < 4; ++q) {
        int m = q*256 + t;             // column index 0..1023
        int l2 = m >> 4, j = m & 15;
        float v = (ss[0][l2][j] + ss[1][l2][j]) + (ss[2][l2][j] + ss[3][l2][j]);
        psum[(size_t)nc*32768 + lb*1024 + m] = v;
    }
}

// ---------------------------------------------------------------------------
// k_csum: s = sum of 16 partials; empty col <=> s==0 (every present addend
// >= exp(-42), far above denormal range); ecol = exp(-K)/s; base = empty ? 1/1024 : 0
__global__ __launch_bounds__(256)
void k_csum(const float* psum, const float* f2, float* ecol, float* base)
{
    int i = blockIdx.x * 256 + threadIdx.x;   // 32768
    float s = 0.f;
    #pragma unroll
    for (int k = 0; k < 16; ++k) s += psum[(size_t)k*32768 + i];
    float x = f2[i];
    float K = fmaxf(x, 0.2f*x) + 12.f;
    bool emp = (s == 0.f);
    ecol[i] = emp ? 0.f : __expf(-K) / s;
    base[i] = emp ? (1.f/1024.f) : 0.f;
}

// ---------------------------------------------------------------------------
// k_pass2: MFMA. outl2[sl=ks*4+l][b][n][f] (f16) = sum_{m in K-half} att[n,m]*h[m,f]
// att generated in registers in A-frag layout: row=lane&31, k=8*(lane>>5)+i.
// grid 512 = ks(2) x l(4) x b(8) x nt(8 tiles of 128 n-rows); block 256 (4 waves: 32n x 64f each)
__global__ __launch_bounds__(256)
void k_pass2(const ushort_t* hT, const u64* maskp, const float* f1,
             const float* f2, const float* ecol, const float* base, __half* outl2)
{
    int blk = blockIdx.x;
    int nt = blk & 7, b = (blk >> 3) & 7, l = (blk >> 6) & 3, ks = blk >> 8;
    int lb = l*8 + b;
    int n0 = nt*128;
    int m0 = ks*512;
    int t = threadIdx.x;
    int w = t >> 6, lane = t & 63;
    int rl = lane & 31, kg = lane >> 5;

    __shared__ float f2t[512], ect[512], bat[512];
    __shared__ ushort_t hl[64][72];   // 64 f x 64 m bf16 chunk, pad 72

    for (int k = 0; k < 2; ++k) {
        int j = t + k*256;
        f2t[j] = f2[lb*1024 + m0 + j];
        ect[j] = ecol[lb*1024 + m0 + j];
        bat[j] = base[lb*1024 + m0 + j];
    }
    int nrow = n0 + w*32 + rl;
    float f1v = f1[lb*1024 + nrow];
    const u64* mrow = maskp + ((size_t)(b*1024 + nrow)*4 + l)*16 + ks*8;

    f32x16 acc0 = {0,0,0,0,0,0,0,0,0,0,0,0,0,0,0,0};
    f32x16 acc1 = {0,0,0,0,0,0,0,0,0,0,0,0,0,0,0,0};

    int hf = t >> 2, hseg = t & 3;
    const ushort_t* hsrc = hT + ((size_t)(lb*64 + hf)) * 1024 + m0 + hseg*16;

    for (int kc = 0; kc < 8; ++kc) {
        __syncthreads();
        {   // stage 64f x 64m bf16 chunk
            const uint4* s = (const uint4*)(hsrc + kc*64);
            uint4 q0 = s[0], q1 = s[1];
            *(uint4*)&hl[hf][hseg*16]     = q0;
            *(uint4*)&hl[hf][hseg*16 + 8] = q1;
        }
        u64 wm = mrow[kc];
        __syncthreads();
        #pragma unroll
        for (int kk = 0; kk < 4; ++kk) {
            int jb = kc*64 + kk*16 + kg*8;
            float4 fa = *(float4*)&f2t[jb];
            float4 fb = *(float4*)&f2t[jb+4];
            float4 ea = *(float4*)&ect[jb];
            float4 eb = *(float4*)&ect[jb+4];
            float4 ba = *(float4*)&bat[jb];
            float4 bb = *(float4*)&bat[jb+4];
            unsigned mb = (unsigned)(wm >> (kk*16 + kg*8)) & 0xffu;
            float xs[8] = {fa.x,fa.y,fa.z,fa.w,fb.x,fb.y,fb.z,fb.w};
            float es[8] = {ea.x,ea.y,ea.z,ea.w,eb.x,eb.y,eb.z,eb.w};
            float bs[8] = {ba.x,ba.y,ba.z,ba.w,bb.x,bb.y,bb.z,bb.w};
            float av[8];
            #pragma unroll
            for (int i = 0; i < 8; ++i) {
                float x = f1v + xs[i];
                x = fmaxf(x, 0.2f * x);          // leaky_relu(0.2)
                float p = __expf(x) * es[i];
                av[i] = (mb & (1u << i)) ? p : bs[i];
            }
            union { unsigned u[4]; short8v s; } af;
            af.u[0] = cvt_pk_bf16(av[0], av[1]);
            af.u[1] = cvt_pk_bf16(av[2], av[3]);
            af.u[2] = cvt_pk_bf16(av[4], av[5]);
            af.u[3] = cvt_pk_bf16(av[6], av[7]);
            short8v b0 = *(short8v*)&hl[rl][kk*16 + kg*8];
            short8v b1 = *(short8v*)&hl[32 + rl][kk*16 + kg*8];
            acc0 = __builtin_amdgcn_mfma_f32_32x32x16_bf16(af.s, b0, acc0, 0, 0, 0);
            acc1 = __builtin_amdgcn_mfma_f32_32x32x16_bf16(af.s, b1, acc1, 0, 0, 0);
        }
    }
    int sl = ks*4 + l;
    __half* op = outl2 + ((size_t)(sl*8 + b) * 1024) * 64;
    #pragma unroll
    for (int r = 0; r < 16; ++r) {
        int row = n0 + w*32 + (r & 3) + 8*(r >> 2) + 4*kg;   // C/D layout (m74/m101)
        op[(size_t)row*64 + rl]      = __float2half(acc0[r]);
        op[(size_t)row*64 + 32 + rl] = __float2half(acc1[r]);
    }
}

// ---------------------------------------------------------------------------
// k_reduce: outpre = sum_{8 slices} outl2 + bias; BN partial sums (LDS + global atomics)
// grid 256 x 256 thr x 8 elems = 524288
__global__ __launch_bounds__(256)
void k_reduce(const __half* outl2, const float* bias, float* outpre, float* bnsum, float* bnsumsq)
{
    int blk = blockIdx.x, t = threadIdx.x;
    __shared__ float red[2][64];
    if (t < 128) red[t >> 6][t & 63] = 0.f;
    __syncthreads();
    size_t idx = (size_t)blk * 2048 + t * 8;
    int fb = (t * 8) & 63;
    float o[8];
    for (int j = 0; j < 8; ++j) o[j] = bias[fb + j];
    #pragma unroll
    for (int sl = 0; sl < 8; ++sl) {
        uint4 u = *(const uint4*)(outl2 + (size_t)sl * 524288 + idx);
        const __half* hh = (const __half*)&u;
        #pragma unroll
        for (int j = 0; j < 8; ++j) o[j] += __half2float(hh[j]);
    }
    *(float4*)(outpre + idx)     = make_float4(o[0], o[1], o[2], o[3]);
    *(float4*)(outpre + idx + 4) = make_float4(o[4], o[5], o[6], o[7]);
    for (int j = 0; j < 8; ++j) {
        atomicAdd(&red[0][fb + j], o[j]);
        atomicAdd(&red[1][fb + j], o[j]*o[j]);
    }
    __syncthreads();
    if (t < 64) { atomicAdd(&bnsum[t], red[0][t]); atomicAdd(&bnsumsq[t], red[1][t]); }
}

// ---------------------------------------------------------------------------
// k_bnapply: main BN+relu (grid 128 covers 524288 elems). Block 0 additionally
// computes gs = gstate@Wg, its batch BN+relu -> out_gs.
__global__ __launch_bounds__(256)
void k_bnapply(const float* outpre, const float* bnsum, const float* bnsumsq,
               const float* gamma, const float* beta, float* out,
               const float* gstate, const float* Wg,
               const float* gamma_g, const float* beta_g, float* out_gs)
{
    int blk = blockIdx.x, t = threadIdx.x;
    __shared__ float gsa[512];
    __shared__ float gmu[64], grs[64];
    if (blk == 0) {
        for (int p = t; p < 512; p += 256) {
            int bb = p >> 6, o = p & 63;
            float acc = 0.f;
            for (int c = 0; c < 128; ++c) acc += gstate[bb*128 + c] * Wg[c*64 + o];
            gsa[p] = acc;
        }
        __syncthreads();
        if (t < 64) {
            float s = 0.f, sq = 0.f;
            for (int bb = 0; bb < 8; ++bb) { float v = gsa[bb*64 + t]; s += v; sq += v*v; }
            float mu = s * 0.125f;
            float var = sq * 0.125f - mu*mu;
            gmu[t] = mu; grs[t] = rsqrtf(var + 1e-5f);
        }
        __syncthreads();
        for (int p = t; p < 512; p += 256) {
            int o = p & 63;
            float v = (gsa[p] - gmu[o]) * grs[o] * gamma_g[o] + beta_g[o];
            out_gs[p] = fmaxf(v, 0.f);
        }
    }
    int f0 = (t * 4) & 63;
    float mu[4], rstd[4], ga[4], be[4];
    for (int j = 0; j < 4; ++j) {
        float sm = bnsum[f0 + j], sq = bnsumsq[f0 + j];
        float m = sm * (1.f / 8192.f);
        float var = sq * (1.f / 8192.f) - m*m;
        mu[j] = m; rstd[j] = rsqrtf(var + 1e-5f);
        ga[j] = gamma[f0 + j]; be[j] = beta[f0 + j];
    }
    for (int g = 0; g < 4; ++g) {
        size_t base = (size_t)blk * 4096 + g * 1024 + t * 4;
        float4 v = *(const float4*)(outpre + base);
        float x[4] = {v.x, v.y, v.z, v.w};
        float y[4];
        for (int j = 0; j < 4; ++j) {
            float z = (x[j] - mu[j]) * rstd[j] * ga[j] + be[j];
            y[j] = fmaxf(z, 0.f);
        }
        *(float4*)(out + base) = make_float4(y[0], y[1], y[2], y[3]);
    }
}

// ---------------------------------------------------------------------------
extern "C" void kernel_launch(void* const* d_in, const int* in_sizes, int n_in,
                              void* d_out, int out_size, void* d_ws, size_t ws_size,
                              hipStream_t stream)
{
    const float* V       = (const float*)d_in[0];
    const float* A       = (const float*)d_in[1];
    const float* gstate  = (const float*)d_in[2];
    const int*   gsize   = (const int*)d_in[3];
    // d_in[4] subgraph_size: unused by reference
    const float* Wg      = (const float*)d_in[5];
    const float* W       = (const float*)d_in[6];
    const float* a1      = (const float*)d_in[7];
    const float* a2      = (const float*)d_in[8];
    const float* bias    = (const float*)d_in[9];
    const float* gamma_n = (const float*)d_in[10];
    const float* beta_n  = (const float*)d_in[11];
    const float* gamma_g = (const float*)d_in[12];
    const float* beta_g  = (const float*)d_in[13];

    char* ws = (char*)d_ws;               // ~22 MB used (ws is ~512 MB)
    float*    f1      = (float*)(ws + 0);
    float*    f2      = (float*)(ws + 131072);
    float*    ecol    = (float*)(ws + 262144);
    float*    base    = (float*)(ws + 393216);
    float*    bnsum   = (float*)(ws + 524288);
    float*    bnsumsq = (float*)(ws + 524544);
    u64*      maskp   = (u64*)  (ws + 525312);      // 4 MB
    ushort_t* hT      = (ushort_t*)(ws + 4719616);  // 4 MB bf16
    float*    psum    = (float*)(ws + 8913920);     // 2 MB (16 partials x 32K)
    __half*   outl2   = (__half*)(ws + 11011072);   // 8 MB (8 slices f16)
    float*    outpre  = (float*)(ws + 19399680);    // 2 MB

    float* out_main = (float*)d_out;
    float* out_gs   = out_main + 524288;

    (void)hipMemsetAsync(bnsum, 0, 512, stream);   // bnsum + bnsumsq
    hipLaunchKernelGGL(k_h,       dim3(256),  dim3(256), 0, stream,
                       V, gsize, gstate, Wg, W, a1, a2, hT, f1, f2);
    hipLaunchKernelGGL(k_mask,    dim3(8192), dim3(256), 0, stream,
                       A, (ushort_t*)maskp);
    hipLaunchKernelGGL(k_colsum,  dim3(512),  dim3(256), 0, stream,
                       (const ushort_t*)maskp, f1, f2, psum);
    hipLaunchKernelGGL(k_csum,    dim3(128),  dim3(256), 0, stream,
                       psum, f2, ecol, base);
    hipLaunchKernelGGL(k_pass2,   dim3(512),  dim3(256), 0, stream,
                       hT, maskp, f1, f2, ecol, base, outl2);
    hipLaunchKernelGGL(k_reduce,  dim3(256),  dim3(256), 0, stream,
                       outl2, bias, outpre, bnsum, bnsumsq);
    hipLaunchKernelGGL(k_bnapply, dim3(128),  dim3(256), 0, stream,
                       outpre, bnsum, bnsumsq, gamma_n, beta_n, out_main,
                       gstate, Wg, gamma_g, beta_g, out_gs);
}